// Round 6
// baseline (361.968 us; speedup 1.0000x reference)
//
#include <hip/hip_runtime.h>
#include <stdint.h>

typedef unsigned short u16;
typedef __attribute__((ext_vector_type(8))) unsigned short u16x8;
typedef __attribute__((ext_vector_type(4))) unsigned short u16x4;
typedef __attribute__((ext_vector_type(2))) __fp16 h16x2;         // cvt_pkrtz result type
typedef __attribute__((ext_vector_type(4))) _Float16 f16x4;
typedef __attribute__((ext_vector_type(8))) _Float16 f16x8;
typedef __attribute__((ext_vector_type(4))) float f32x4;

#define MFMA16F16(a,b,c)  __builtin_amdgcn_mfma_f32_16x16x16f16((a),(b),(c),0,0,0)
#define MFMA32F16(a,b,c)  __builtin_amdgcn_mfma_f32_16x16x32_f16((a),(b),(c),0,0,0)

__device__ __forceinline__ f32x4 f4zero() {
    f32x4 z; z[0]=0.f; z[1]=0.f; z[2]=0.f; z[3]=0.f; return z;
}
__device__ __forceinline__ u16x8 cvth8(float4 a, float4 b) {   // 8x fp32->fp16 (pkrtz)
    union { h16x2 h[4]; u16x8 u; } U;
    U.h[0] = __builtin_amdgcn_cvt_pkrtz(a.x, a.y);
    U.h[1] = __builtin_amdgcn_cvt_pkrtz(a.z, a.w);
    U.h[2] = __builtin_amdgcn_cvt_pkrtz(b.x, b.y);
    U.h[3] = __builtin_amdgcn_cvt_pkrtz(b.z, b.w);
    return U.u;
}

#define GLDS(gp, lp) __builtin_amdgcn_global_load_lds( \
    (const __attribute__((address_space(1))) void*)(gp), \
    (__attribute__((address_space(3))) void*)(lp), 16, 0, 0)

#define QSC 0.1803368801111601f   // (1/8) * log2(e), folded into Q at GEMM epilogue

// ---------------------------------------------------------------------------
// fp32 -> f16 weight pre-convert: 4 x 1M elems (weights only — X is converted
// inline in gemm_qkv's reg-staged pipeline; the old conv_x pass was 144 MB of
// pure-overhead traffic once the T14 staging hid the cvt under MFMA)
// ---------------------------------------------------------------------------
__global__ __launch_bounds__(256) void conv_w(
    const float* __restrict__ w0, const float* __restrict__ w1,
    const float* __restrict__ w2, const float* __restrict__ w3,
    u16* __restrict__ out)
{
    const int t = blockIdx.x >> 8;
    const float* src = (t == 0) ? w0 : (t == 1) ? w1 : (t == 2) ? w2 : w3;
    const size_t idx = (size_t)(blockIdx.x & 255) * 4096 + (size_t)threadIdx.x * 16;
    u16* dst = out + (size_t)t * 1048576 + idx;
    float4 a0 = *(const float4*)(src + idx);
    float4 a1 = *(const float4*)(src + idx + 4);
    float4 a2 = *(const float4*)(src + idx + 8);
    float4 a3 = *(const float4*)(src + idx + 12);
    *(u16x8*)dst       = cvth8(a0, a1);
    *(u16x8*)(dst + 8) = cvth8(a2, a3);
}

// ---------------------------------------------------------------------------
// Fused QKV NT-GEMM, BK=32, TRIPLE-BUFFERED counted-vmcnt pipeline (T3/T4):
// one raw s_barrier per K-tile; tile t+2 staged while computing t; vmcnt never
// drained to 0 in the main loop. LDS [128][32] linear (conflict-free).
// MODE 0: X,W fp32 inline (old 2-barrier loop, small-ws fallback).
// MODE 1: X fp32 reg-staged (T14 early-issue/late-write) + W f16 GLDS. [main]
// t==0 output pre-scaled by QSC. t<2 -> (B,H,S,Dk); t==2 -> (B,H,Dk,S).
// ---------------------------------------------------------------------------
template<int MODE>
__global__ __launch_bounds__(256, 3) void gemm_qkv(
    const float* __restrict__ Qf, const float* __restrict__ Kf, const float* __restrict__ Vf,
    const u16* __restrict__ wc,
    const float* __restrict__ Wqf, const float* __restrict__ Wkf, const float* __restrict__ Wvf,
    const float* __restrict__ bq, const float* __restrict__ bk, const float* __restrict__ bv,
    u16* __restrict__ qhp, u16* __restrict__ khp, u16* __restrict__ vtp)
{
    __shared__ __align__(16) u16 smem[24576];   // 3 x (As[128][32] | Bs[128][32])
    u16* Ct = smem;                             // [128][136] epilogue alias

    const int t  = blockIdx.y >> 3;
    const int n0 = (blockIdx.y & 7) * 128;
    const int m0 = blockIdx.x * 128;
    const float* X    = (t == 0) ? Qf : (t == 1) ? Kf : Vf;
    const float* Wf   = (t == 0) ? Wqf : (t == 1) ? Wkf : Wvf;
    const float* bias = (t == 0) ? bq : (t == 1) ? bk : bv;
    const u16*   Wb   = wc + (size_t)t * 1048576;
    u16*         dst  = (t == 0) ? qhp : (t == 1) ? khp : vtp;
    const float  scl  = (t == 0) ? QSC : 1.0f;

    const int tid  = threadIdx.x;
    const int wave = tid >> 6, lane = tid & 63;
    const int quad = lane >> 4, l16 = lane & 15;
    const int wm = (wave >> 1) * 64, wn = (wave & 1) * 64;

    // GLDS staging: wave covers rows [wave*32, wave*32+32), 2 instrs/operand
    const int srow = lane >> 2;                     // 0..15
    const size_t scol = (size_t)(lane & 3) * 8;     // elem offset in row
    // fp32 reg-staging map: row = tid>>1, 16-elem half hh
    const int sr = tid >> 1, hh = tid & 1;

    f32x4 acc[4][4];
    for (int i = 0; i < 4; i++) for (int j = 0; j < 4; j++) acc[i][j] = f4zero();

    auto stageB = [&](int b, int kt) {
        GLDS(Wb + (size_t)(n0 + wave * 32 +      srow) * 1024 + kt * 32 + scol,
             smem + b * 8192 + 4096 + wave * 1024);
        GLDS(Wb + (size_t)(n0 + wave * 32 + 16 + srow) * 1024 + kt * 32 + scol,
             smem + b * 8192 + 4096 + wave * 1024 + 512);
    };
    float4 xr_[4];
    auto loadX = [&](int kt) {
        const float* p = X + (size_t)(m0 + sr) * 1024 + kt * 32 + hh * 16;
        xr_[0] = *(const float4*)(p);     xr_[1] = *(const float4*)(p + 4);
        xr_[2] = *(const float4*)(p + 8); xr_[3] = *(const float4*)(p + 12);
    };
    auto writeX = [&](int b) {
        u16* d = smem + b * 8192 + sr * 32 + hh * 16;
        *(u16x8*)d       = cvth8(xr_[0], xr_[1]);
        *(u16x8*)(d + 8) = cvth8(xr_[2], xr_[3]);
    };
    auto comp = [&](int b) {
        const u16* As = smem + b * 8192;
        const u16* Bs = As + 4096;
        f16x8 af[4], bfr[4];
#pragma unroll
        for (int i = 0; i < 4; i++) {
            af[i]  = *(const f16x8*)(As + (wm + i * 16 + l16) * 32 + quad * 8);
            bfr[i] = *(const f16x8*)(Bs + (wn + i * 16 + l16) * 32 + quad * 8);
        }
        __builtin_amdgcn_s_setprio(1);
#pragma unroll
        for (int i = 0; i < 4; i++)
#pragma unroll
            for (int j = 0; j < 4; j++)
                acc[i][j] = MFMA32F16(af[i], bfr[j], acc[i][j]);
        __builtin_amdgcn_s_setprio(0);
    };

    if (MODE == 0) {
        // fallback: classic 2-barrier inline loop, buffer 0 only
        for (int kt = 0; kt < 32; ++kt) {
            loadX(kt); writeX(0);
            const float* p = Wf + (size_t)(n0 + sr) * 1024 + kt * 32 + hh * 16;
            float4 b0 = *(const float4*)(p);     float4 b1 = *(const float4*)(p + 4);
            float4 b2 = *(const float4*)(p + 8); float4 b3 = *(const float4*)(p + 12);
            u16* d = smem + 4096 + sr * 32 + hh * 16;
            *(u16x8*)d       = cvth8(b0, b1);
            *(u16x8*)(d + 8) = cvth8(b2, b3);
            __syncthreads();
            comp(0);
            __syncthreads();
        }
    } else {
        // prologue: W tiles 0,1 into bufs 0,1 (GLDS); X tile 0 reg->buf0
        stageB(0, 0);
        stageB(1, 1);
        loadX(0); writeX(0);
        int bA = 0, bB = 1, bC = 2;
        for (int kt = 0; kt < 31; ++kt) {
            asm volatile("s_waitcnt vmcnt(2) lgkmcnt(0)" ::: "memory");
            __builtin_amdgcn_s_barrier();
            __builtin_amdgcn_sched_barrier(0);
            loadX(kt + 1);                           // issue early (T14)
            if (kt < 30) stageB(bC, kt + 2);
            comp(bA);
            writeX(bB);                              // write late, drained next wait
            int tmp = bA; bA = bB; bB = bC; bC = tmp;
        }
        asm volatile("s_waitcnt vmcnt(0) lgkmcnt(0)" ::: "memory");
        __builtin_amdgcn_s_barrier();
        __builtin_amdgcn_sched_barrier(0);
        comp(bA);                                    // tile 31
    }
    __syncthreads();   // all reads done before Ct alias writes

    // f16 epilogue via LDS (scale folded for Q)
#pragma unroll
    for (int i = 0; i < 4; i++) {
        const int row = wm + i * 16 + quad * 4;
#pragma unroll
        for (int j = 0; j < 4; j++) {
            const int col = wn + j * 16 + l16;
            const float bv2 = bias[n0 + col];
#pragma unroll
            for (int r = 0; r < 2; r++) {
                union { h16x2 h; unsigned u; } P;
                P.h = __builtin_amdgcn_cvt_pkrtz((acc[i][j][2*r] + bv2) * scl,
                                                 (acc[i][j][2*r+1] + bv2) * scl);
                Ct[(row + 2*r)     * 136 + col] = (u16)(P.u & 0xFFFF);
                Ct[(row + 2*r + 1) * 136 + col] = (u16)(P.u >> 16);
            }
        }
    }
    __syncthreads();

    if (t < 2) {              // (B,H,S,Dk)
        const int row = tid >> 1, half = tid & 1;
        const int m = m0 + row, b = m >> 11, s = m & 2047;
        const int h = (n0 >> 6) + half;
        u16* o = dst + ((size_t)(b * 16 + h) * 2048 + s) * 64;
        const u16* src = Ct + row * 136 + half * 64;
#pragma unroll
        for (int j = 0; j < 64; j += 8) *(u16x8*)(o + j) = *(const u16x8*)(src + j);
    } else {                  // (B,H,Dk,S) transposed V
        const int col = tid >> 1, shalf = tid & 1;
        const int h = (n0 >> 6) + (col >> 6), d = col & 63;
        const int mb = m0 + shalf * 64, b = mb >> 11, sb = mb & 2047;
        u16* o = dst + (size_t)((b * 16 + h) * 64 + d) * 2048 + sb;
#pragma unroll
        for (int j0 = 0; j0 < 64; j0 += 8) {
            u16x8 tv;
#pragma unroll
            for (int j = 0; j < 8; j++) tv[j] = Ct[(shalf * 64 + j0 + j) * 136 + col];
            *(u16x8*)(o + j0) = tv;
        }
    }
}

// ---------------------------------------------------------------------------
// O-GEMM, BK=32, same triple-buffered counted-vmcnt pipeline.
// MODE 2: X,W f16 GLDS.  MODE 1: X f16 GLDS + W fp32 reg-staged.
// ---------------------------------------------------------------------------
template<int MODE>
__global__ __launch_bounds__(256, 3) void gemm_o(
    const u16* __restrict__ Xb, const u16* __restrict__ wcO,
    const float* __restrict__ Wf, const float* __restrict__ bias,
    float* __restrict__ out)
{
    __shared__ __align__(16) u16 smem[24576];   // 3 x (As | Bs)

    const int tid  = threadIdx.x;
    const int wave = tid >> 6, lane = tid & 63;
    const int quad = lane >> 4, l16 = lane & 15;
    const int m0 = blockIdx.x * 128, n0 = blockIdx.y * 128;
    const int wm = (wave >> 1) * 64, wn = (wave & 1) * 64;

    const int srow = lane >> 2;
    const size_t scol = (size_t)(lane & 3) * 8;
    const int sr = tid >> 1, hh = tid & 1;

    f32x4 acc[4][4];
    for (int i = 0; i < 4; i++) for (int j = 0; j < 4; j++) acc[i][j] = f4zero();

    auto stageA = [&](int b, int kt) {
        GLDS(Xb + (size_t)(m0 + wave * 32 +      srow) * 1024 + kt * 32 + scol,
             smem + b * 8192 + wave * 1024);
        GLDS(Xb + (size_t)(m0 + wave * 32 + 16 + srow) * 1024 + kt * 32 + scol,
             smem + b * 8192 + wave * 1024 + 512);
    };
    auto stageB = [&](int b, int kt) {
        GLDS(wcO + (size_t)(n0 + wave * 32 +      srow) * 1024 + kt * 32 + scol,
             smem + b * 8192 + 4096 + wave * 1024);
        GLDS(wcO + (size_t)(n0 + wave * 32 + 16 + srow) * 1024 + kt * 32 + scol,
             smem + b * 8192 + 4096 + wave * 1024 + 512);
    };
    float4 wr_[4];
    auto loadW = [&](int kt) {
        const float* p = Wf + (size_t)(n0 + sr) * 1024 + kt * 32 + hh * 16;
        wr_[0] = *(const float4*)(p);     wr_[1] = *(const float4*)(p + 4);
        wr_[2] = *(const float4*)(p + 8); wr_[3] = *(const float4*)(p + 12);
    };
    auto writeW = [&](int b) {
        u16* d = smem + b * 8192 + 4096 + sr * 32 + hh * 16;
        *(u16x8*)d       = cvth8(wr_[0], wr_[1]);
        *(u16x8*)(d + 8) = cvth8(wr_[2], wr_[3]);
    };
    auto comp = [&](int b) {
        const u16* As = smem + b * 8192;
        const u16* Bs = As + 4096;
        f16x8 af[4], bfr[4];
#pragma unroll
        for (int i = 0; i < 4; i++) {
            af[i]  = *(const f16x8*)(As + (wm + i * 16 + l16) * 32 + quad * 8);
            bfr[i] = *(const f16x8*)(Bs + (wn + i * 16 + l16) * 32 + quad * 8);
        }
        __builtin_amdgcn_s_setprio(1);
#pragma unroll
        for (int i = 0; i < 4; i++)
#pragma unroll
            for (int j = 0; j < 4; j++)
                acc[i][j] = MFMA32F16(af[i], bfr[j], acc[i][j]);
        __builtin_amdgcn_s_setprio(0);
    };

    // prologue
    stageA(0, 0);
    if (MODE == 2) stageB(0, 0);
    stageA(1, 1);
    if (MODE == 2) stageB(1, 1);
    if (MODE == 1) { loadW(0); writeW(0); }
    int bA = 0, bB = 1, bC = 2;
    for (int kt = 0; kt < 31; ++kt) {
        if (MODE == 2) asm volatile("s_waitcnt vmcnt(4) lgkmcnt(0)" ::: "memory");
        else           asm volatile("s_waitcnt vmcnt(2) lgkmcnt(0)" ::: "memory");
        __builtin_amdgcn_s_barrier();
        __builtin_amdgcn_sched_barrier(0);
        if (MODE == 1) loadW(kt + 1);
        if (kt < 30) {
            stageA(bC, kt + 2);
            if (MODE == 2) stageB(bC, kt + 2);
        }
        comp(bA);
        if (MODE == 1) writeW(bB);
        int tmp = bA; bA = bB; bB = bC; bC = tmp;
    }
    asm volatile("s_waitcnt vmcnt(0) lgkmcnt(0)" ::: "memory");
    __builtin_amdgcn_s_barrier();
    __builtin_amdgcn_sched_barrier(0);
    comp(bA);

#pragma unroll
    for (int i = 0; i < 4; i++)
#pragma unroll
        for (int j = 0; j < 4; j++) {
            const int col = wn + j * 16 + l16;
            const float bv = bias[n0 + col];
#pragma unroll
            for (int r = 0; r < 4; r++)
                out[(size_t)(m0 + wm + i * 16 + quad * 4 + r) * 1024 + n0 + col] = acc[i][j][r] + bv;
        }
}

// ---------------------------------------------------------------------------
// Flash attention: fixed-shift softmax, l via ones-MFMA.
// PHASE-SPLIT tile body: phase 1 = all QK^T MFMAs + softmax (nt iterations
// independent -> exp2 of nt overlaps MFMA of nt+1); phase 2 = dense cluster
// of 40 register-only PV/lacc MFMAs. pf[4][2] statically indexed (rule #20).
// K staged via swizzled-source GLDS; V reg-staged (T14); one barrier/tile.
// ---------------------------------------------------------------------------
__global__ __launch_bounds__(256, 4) void attn_fused(
    const u16* __restrict__ qh, const u16* __restrict__ kh,
    const u16* __restrict__ vth, const int* __restrict__ mask,
    u16* __restrict__ xout)
{
    __shared__ __align__(16) u16 Ksh[2][4096];    // [buf][row*64 + swz-chunk] linear
    __shared__ __align__(16) u16 Vsh[2][4352];    // [buf][d*68 + key] pad 68
    __shared__ float mshf[2][64];                 // per-key additive bias

    const int tid = threadIdx.x, wave = tid >> 6, lane = tid & 63;
    const int quad = lane >> 4, l16 = lane & 15;

    // XCD-aware remap: flat%8 == bh%8 for all 16 q-blocks of a given bh
    const int flat = blockIdx.x + (blockIdx.y << 4);   // gridDim.x == 16
    const int xr = flat & 7, xc_ = flat >> 3;
    const int qb = xc_ & 15, bh = xr + ((xc_ >> 4) << 3);
    const int b = bh >> 4, h = bh & 15;
    const int wq = qb * 128 + wave * 32;

    f16x8 qf[2][2];
#pragma unroll
    for (int qg = 0; qg < 2; qg++)
#pragma unroll
        for (int kc = 0; kc < 2; kc++)
            qf[qg][kc] = *(const f16x8*)(qh + ((size_t)bh * 2048 + wq + qg * 16 + l16) * 64
                                         + kc * 32 + quad * 8);

    f32x4 o[2][4];
#pragma unroll
    for (int qg = 0; qg < 2; qg++)
        for (int dt = 0; dt < 4; dt++) o[qg][dt] = f4zero();
    f32x4 lacc[2]; lacc[0] = f4zero(); lacc[1] = f4zero();
    f16x4 ones;
    ones[0] = (_Float16)1.f; ones[1] = (_Float16)1.f;
    ones[2] = (_Float16)1.f; ones[3] = (_Float16)1.f;

    const int klr = lane >> 3;                              // 0..7
    const size_t kgoff = (size_t)((lane & 7) ^ klr) << 3;   // elem offset in row
    const u16* kgb = kh + (size_t)bh * 2048 * 64;

    const int skey = tid >> 2, sc = (tid & 3) * 16;
    const u16* vg = vth + ((size_t)bh * 64 + skey) * 2048 + sc;
    const int mrow = b * 2048;

    {
        GLDS(kgb + (size_t)(wave * 16 + klr) * 64 + kgoff,     &Ksh[0][wave * 1024]);
        GLDS(kgb + (size_t)(wave * 16 + 8 + klr) * 64 + kgoff, &Ksh[0][wave * 1024 + 512]);
        const u16x8 v0 = *(const u16x8*)(vg);
        const u16x8 v1 = *(const u16x8*)(vg + 8);
        u16* vd = &Vsh[0][skey * 68 + sc];
        *(u16x4*)(vd)      = (u16x4){v0[0], v0[1], v0[2], v0[3]};
        *(u16x4*)(vd + 4)  = (u16x4){v0[4], v0[5], v0[6], v0[7]};
        *(u16x4*)(vd + 8)  = (u16x4){v1[0], v1[1], v1[2], v1[3]};
        *(u16x4*)(vd + 12) = (u16x4){v1[4], v1[5], v1[6], v1[7]};
        if (tid < 64) mshf[0][tid] = mask[mrow + tid] ? -10.0f : -1.0e30f;
    }
    __syncthreads();

    for (int t = 0; t < 32; ++t) {
        const int cur = t & 1;
        const u16* Kc = &Ksh[cur][0];
        const u16* Vc = &Vsh[cur][0];

        u16x8 v0, v1; int mreg = 1;
        const int kk2 = (t + 1) * 64;
        if (t < 31) {
            GLDS(kgb + (size_t)(kk2 + wave * 16 + klr) * 64 + kgoff,
                 &Ksh[cur ^ 1][wave * 1024]);
            GLDS(kgb + (size_t)(kk2 + wave * 16 + 8 + klr) * 64 + kgoff,
                 &Ksh[cur ^ 1][wave * 1024 + 512]);
            v0 = *(const u16x8*)(vg + kk2);
            v1 = *(const u16x8*)(vg + kk2 + 8);
            if (tid < 64) mreg = mask[mrow + kk2 + tid];
        }

        __builtin_amdgcn_s_setprio(1);
        // ---- phase 1: all QK^T + softmax -> pf[4][2] ----
        f16x4 pf[4][2];
#pragma unroll
        for (int nt = 0; nt < 4; nt++) {
            const int kro = (nt * 16 + l16) * 64;
            const f16x8 kf0 = *(const f16x8*)(Kc + kro + ((quad ^ (l16 & 7)) << 3));
            const f16x8 kf1 = *(const f16x8*)(Kc + kro + (((quad ^ 4) ^ (l16 & 7)) << 3));
            const float4 mb = *(const float4*)(&mshf[cur][nt * 16 + quad * 4]);
#pragma unroll
            for (int qg = 0; qg < 2; qg++) {
                f32x4 z;
                z[0] = mb.x; z[1] = mb.y; z[2] = mb.z; z[3] = mb.w;
                z = MFMA32F16(kf0, qf[qg][0], z);
                z = MFMA32F16(kf1, qf[qg][1], z);
                union { h16x2 h[2]; f16x4 v; } U;
                U.h[0] = __builtin_amdgcn_cvt_pkrtz(__builtin_amdgcn_exp2f(z[0]),
                                                    __builtin_amdgcn_exp2f(z[1]));
                U.h[1] = __builtin_amdgcn_cvt_pkrtz(__builtin_amdgcn_exp2f(z[2]),
                                                    __builtin_amdgcn_exp2f(z[3]));
                pf[nt][qg] = U.v;
            }
        }
        // ---- phase 2: dense PV + l MFMA cluster (register-only inputs) ----
#pragma unroll
        for (int nt = 0; nt < 4; nt++) {
            lacc[0] = MFMA16F16(ones, pf[nt][0], lacc[0]);
            lacc[1] = MFMA16F16(ones, pf[nt][1], lacc[1]);
        }
#pragma unroll
        for (int dt = 0; dt < 4; dt++) {
#pragma unroll
            for (int nt = 0; nt < 4; nt++) {
                const f16x4 vf = *(const f16x4*)(Vc + (dt * 16 + l16) * 68 + nt * 16 + quad * 4);
                o[0][dt] = MFMA16F16(vf, pf[nt][0], o[0][dt]);
                o[1][dt] = MFMA16F16(vf, pf[nt][1], o[1][dt]);
            }
        }
        __builtin_amdgcn_s_setprio(0);

        if (t < 31) {
            u16* vd = &Vsh[cur ^ 1][skey * 68 + sc];
            *(u16x4*)(vd)      = (u16x4){v0[0], v0[1], v0[2], v0[3]};
            *(u16x4*)(vd + 4)  = (u16x4){v0[4], v0[5], v0[6], v0[7]};
            *(u16x4*)(vd + 8)  = (u16x4){v1[0], v1[1], v1[2], v1[3]};
            *(u16x4*)(vd + 12) = (u16x4){v1[4], v1[5], v1[6], v1[7]};
            if (tid < 64) mshf[cur ^ 1][tid] = mreg ? -10.0f : -1.0e30f;
        }
        __syncthreads();
    }

#pragma unroll
    for (int qg = 0; qg < 2; qg++) {
        const float inv = 1.0f / lacc[qg][0];
        const int row = wq + qg * 16 + l16;
        u16* op = xout + ((size_t)b * 2048 + row) * 1024 + h * 64;
#pragma unroll
        for (int dt = 0; dt < 4; dt++) {
            union { h16x2 h[2]; u16x4 u; } U;
            U.h[0] = __builtin_amdgcn_cvt_pkrtz(o[qg][dt][0] * inv, o[qg][dt][1] * inv);
            U.h[1] = __builtin_amdgcn_cvt_pkrtz(o[qg][dt][2] * inv, o[qg][dt][3] * inv);
            *(u16x4*)(op + dt * 16 + quad * 4) = U.u;
        }
    }
}

extern "C" void kernel_launch(void* const* d_in, const int* in_sizes, int n_in,
                              void* d_out, int out_size, void* d_ws, size_t ws_size,
                              hipStream_t stream)
{
    const float* Q   = (const float*)d_in[0];
    const float* K   = (const float*)d_in[1];
    const float* V   = (const float*)d_in[2];
    const int*   msk = (const int*)d_in[3];
    const float* Wq  = (const float*)d_in[4];
    const float* bq  = (const float*)d_in[5];
    const float* Wk  = (const float*)d_in[6];
    const float* bk  = (const float*)d_in[7];
    const float* Wv  = (const float*)d_in[8];
    const float* bv  = (const float*)d_in[9];
    const float* Wo  = (const float*)d_in[10];
    const float* bo  = (const float*)d_in[11];

    u16* base = (u16*)d_ws;
    dim3 blk(256);
    dim3 gq(64, 24);         // fused QKV: 64 m-tiles x (3 tensors x 8 n-tiles)
    dim3 ga(16, 64);         // attn: 2048/128 q-blocks x BH
    dim3 go(64, 8);          // O-GEMM

    if (ws_size >= ((size_t)72 << 20)) {
        // wc(8M) + qkv(48M) + xs(16M) = 72 MiB
        u16* wc  = base;                                // 4x1M f16 weights
        u16* qhp = base + 4194304;                      // (B,H,S,64) f16
        u16* khp = qhp + 8388608;
        u16* vtp = khp + 8388608;                       // (B,H,64,S) f16
        u16* xs  = vtp + 8388608;                       // (B,S,1024) f16
        conv_w<<<1024, blk, 0, stream>>>(Wq, Wk, Wv, Wo, wc);
        gemm_qkv<1><<<gq, blk, 0, stream>>>(Q, K, V, wc,
            nullptr, nullptr, nullptr, bq, bk, bv, qhp, khp, vtp);
        attn_fused<<<ga, blk, 0, stream>>>(qhp, khp, vtp, msk, xs);
        gemm_o<2><<<go, blk, 0, stream>>>(xs, wc + 3 * 1048576, nullptr, bo, (float*)d_out);
    } else {
        u16* qhp = base;
        u16* khp = qhp + 8388608;
        u16* vtp = khp + 8388608;
        u16* xs  = vtp + 8388608;
        gemm_qkv<0><<<gq, blk, 0, stream>>>(Q, K, V, nullptr,
            Wq, Wk, Wv, bq, bk, bv, qhp, khp, vtp);
        attn_fused<<<ga, blk, 0, stream>>>(qhp, khp, vtp, msk, xs);
        gemm_o<1><<<go, blk, 0, stream>>>(xs, nullptr, Wo, bo, (float*)d_out);
    }
}

// Round 7
// 345.939 us; speedup vs baseline: 1.0463x; 1.0463x over previous
//
#include <hip/hip_runtime.h>
#include <stdint.h>

typedef unsigned short u16;
typedef __attribute__((ext_vector_type(8))) unsigned short u16x8;
typedef __attribute__((ext_vector_type(4))) unsigned short u16x4;
typedef __attribute__((ext_vector_type(2))) __fp16 h16x2;         // cvt_pkrtz result type
typedef __attribute__((ext_vector_type(4))) _Float16 f16x4;
typedef __attribute__((ext_vector_type(8))) _Float16 f16x8;
typedef __attribute__((ext_vector_type(4))) float f32x4;

#define MFMA16F16(a,b,c)  __builtin_amdgcn_mfma_f32_16x16x16f16((a),(b),(c),0,0,0)
#define MFMA32F16(a,b,c)  __builtin_amdgcn_mfma_f32_16x16x32_f16((a),(b),(c),0,0,0)

__device__ __forceinline__ f32x4 f4zero() {
    f32x4 z; z[0]=0.f; z[1]=0.f; z[2]=0.f; z[3]=0.f; return z;
}
__device__ __forceinline__ u16x8 cvth8(float4 a, float4 b) {   // 8x fp32->fp16 (pkrtz)
    union { h16x2 h[4]; u16x8 u; } U;
    U.h[0] = __builtin_amdgcn_cvt_pkrtz(a.x, a.y);
    U.h[1] = __builtin_amdgcn_cvt_pkrtz(a.z, a.w);
    U.h[2] = __builtin_amdgcn_cvt_pkrtz(b.x, b.y);
    U.h[3] = __builtin_amdgcn_cvt_pkrtz(b.z, b.w);
    return U.u;
}

#define GLDS(gp, lp) __builtin_amdgcn_global_load_lds( \
    (const __attribute__((address_space(1))) void*)(gp), \
    (__attribute__((address_space(3))) void*)(lp), 16, 0, 0)

#define QSC 0.1803368801111601f   // (1/8) * log2(e), folded into Q at GEMM epilogue

// ---------------------------------------------------------------------------
// fp32 -> f16 weight pre-convert: 4 x 1M elems (weights only)
// ---------------------------------------------------------------------------
__global__ __launch_bounds__(256) void conv_w(
    const float* __restrict__ w0, const float* __restrict__ w1,
    const float* __restrict__ w2, const float* __restrict__ w3,
    u16* __restrict__ out)
{
    const int t = blockIdx.x >> 8;
    const float* src = (t == 0) ? w0 : (t == 1) ? w1 : (t == 2) ? w2 : w3;
    const size_t idx = (size_t)(blockIdx.x & 255) * 4096 + (size_t)threadIdx.x * 16;
    u16* dst = out + (size_t)t * 1048576 + idx;
    float4 a0 = *(const float4*)(src + idx);
    float4 a1 = *(const float4*)(src + idx + 4);
    float4 a2 = *(const float4*)(src + idx + 8);
    float4 a3 = *(const float4*)(src + idx + 12);
    *(u16x8*)dst       = cvth8(a0, a1);
    *(u16x8*)(dst + 8) = cvth8(a2, a3);
}

// ---------------------------------------------------------------------------
// Fused QKV NT-GEMM, BK=32, triple-buffered LDS + 2-DEEP X REGISTER PIPELINE:
// iter kt: {vmcnt(6) wait; barrier; loadX(kt+2)->regset; stageB(kt+2) GLDS;
// comp(kt); writeX(kt+1) from OTHER regset (loaded a full iter ago)}.
// X loads get ~1 iteration of latency cover; vmcnt never drains below 6 in
// steady state (round-6 bug: same-iter load->write forced a drain per tile).
// X LDS staging at lane byte addr = tid*16 (contiguous, conflict-free).
// MODE 0: fp32 inline fallback.  MODE 1: main path.
// t==0 output pre-scaled by QSC. t<2 -> (B,H,S,Dk); t==2 -> (B,H,Dk,S).
// ---------------------------------------------------------------------------
template<int MODE>
__global__ __launch_bounds__(256, 3) void gemm_qkv(
    const float* __restrict__ Qf, const float* __restrict__ Kf, const float* __restrict__ Vf,
    const u16* __restrict__ wc,
    const float* __restrict__ Wqf, const float* __restrict__ Wkf, const float* __restrict__ Wvf,
    const float* __restrict__ bq, const float* __restrict__ bk, const float* __restrict__ bv,
    u16* __restrict__ qhp, u16* __restrict__ khp, u16* __restrict__ vtp)
{
    __shared__ __align__(16) u16 smem[24576];   // 3 x (As[128][32] | Bs[128][32])
    u16* Ct = smem;                             // [128][136] epilogue alias

    const int t  = blockIdx.y >> 3;
    const int n0 = (blockIdx.y & 7) * 128;
    const int m0 = blockIdx.x * 128;
    const float* X    = (t == 0) ? Qf : (t == 1) ? Kf : Vf;
    const float* Wf   = (t == 0) ? Wqf : (t == 1) ? Wkf : Wvf;
    const float* bias = (t == 0) ? bq : (t == 1) ? bk : bv;
    const u16*   Wb   = wc + (size_t)t * 1048576;
    u16*         dst  = (t == 0) ? qhp : (t == 1) ? khp : vtp;
    const float  scl  = (t == 0) ? QSC : 1.0f;

    const int tid  = threadIdx.x;
    const int wave = tid >> 6, lane = tid & 63;
    const int quad = lane >> 4, l16 = lane & 15;
    const int wm = (wave >> 1) * 64, wn = (wave & 1) * 64;

    // GLDS staging (W): wave covers rows [wave*32, wave*32+32)
    const int srow = lane >> 2;                     // 0..15
    const size_t scol = (size_t)(lane & 3) * 8;     // elem offset in row
    // X reg-staging map: lane covers rows sr2 and 64+sr2, 8-elem chunk c2;
    // LDS byte addr = tid*16 (contiguous across wave -> conflict-free writes)
    const int sr2 = tid >> 2, c2 = tid & 3;
    const float* Xb1 = X + (size_t)(m0 + sr2) * 1024 + c2 * 8;
    const float* Xb2 = Xb1 + (size_t)64 * 1024;
    // MODE0 W inline map
    const int sr = tid >> 1, hh = tid & 1;

    f32x4 acc[4][4];
    for (int i = 0; i < 4; i++) for (int j = 0; j < 4; j++) acc[i][j] = f4zero();

    auto stageB = [&](int b, int kt) {
        GLDS(Wb + (size_t)(n0 + wave * 32 +      srow) * 1024 + kt * 32 + scol,
             smem + b * 8192 + 4096 + wave * 1024);
        GLDS(Wb + (size_t)(n0 + wave * 32 + 16 + srow) * 1024 + kt * 32 + scol,
             smem + b * 8192 + 4096 + wave * 1024 + 512);
    };
    float4 xa_[4], xb_[4];
    auto loadXA = [&](int kt) {
        xa_[0] = *(const float4*)(Xb1 + kt * 32);     xa_[1] = *(const float4*)(Xb1 + kt * 32 + 4);
        xa_[2] = *(const float4*)(Xb2 + kt * 32);     xa_[3] = *(const float4*)(Xb2 + kt * 32 + 4);
    };
    auto loadXB = [&](int kt) {
        xb_[0] = *(const float4*)(Xb1 + kt * 32);     xb_[1] = *(const float4*)(Xb1 + kt * 32 + 4);
        xb_[2] = *(const float4*)(Xb2 + kt * 32);     xb_[3] = *(const float4*)(Xb2 + kt * 32 + 4);
    };
    auto writeXA = [&](int b) {
        u16* d = smem + b * 8192 + sr2 * 32 + c2 * 8;   // byte addr = tid*16
        *(u16x8*)d          = cvth8(xa_[0], xa_[1]);
        *(u16x8*)(d + 2048) = cvth8(xa_[2], xa_[3]);    // rows 64..127
    };
    auto writeXB = [&](int b) {
        u16* d = smem + b * 8192 + sr2 * 32 + c2 * 8;
        *(u16x8*)d          = cvth8(xb_[0], xb_[1]);
        *(u16x8*)(d + 2048) = cvth8(xb_[2], xb_[3]);
    };
    auto comp = [&](int b) {
        const u16* As = smem + b * 8192;
        const u16* Bs = As + 4096;
        f16x8 af[4], bfr[4];
#pragma unroll
        for (int i = 0; i < 4; i++) {
            af[i]  = *(const f16x8*)(As + (wm + i * 16 + l16) * 32 + quad * 8);
            bfr[i] = *(const f16x8*)(Bs + (wn + i * 16 + l16) * 32 + quad * 8);
        }
        __builtin_amdgcn_s_setprio(1);
#pragma unroll
        for (int i = 0; i < 4; i++)
#pragma unroll
            for (int j = 0; j < 4; j++)
                acc[i][j] = MFMA32F16(af[i], bfr[j], acc[i][j]);
        __builtin_amdgcn_s_setprio(0);
    };

    if (MODE == 0) {
        // fallback: classic 2-barrier inline loop, buffer 0 only
        for (int kt = 0; kt < 32; ++kt) {
            loadXA(kt); writeXA(0);
            const float* p = Wf + (size_t)(n0 + sr) * 1024 + kt * 32 + hh * 16;
            float4 b0 = *(const float4*)(p);     float4 b1 = *(const float4*)(p + 4);
            float4 b2 = *(const float4*)(p + 8); float4 b3 = *(const float4*)(p + 12);
            u16* d = smem + 4096 + sr * 32 + hh * 16;
            *(u16x8*)d       = cvth8(b0, b1);
            *(u16x8*)(d + 8) = cvth8(b2, b3);
            __syncthreads();
            comp(0);
            __syncthreads();
        }
    } else {
        // prologue: W tiles 0,1 via GLDS; X tile 0 -> buf0; X tile 1 -> regs B
        stageB(0, 0);
        stageB(1, 1);
        loadXA(0); writeXA(0);
        loadXB(1);
        int bA = 0, bB = 1, bC = 2;
        for (int kt = 0; kt < 30; kt += 2) {
            // even iter: load tile kt+2 -> A, write tile kt+1 from B
            asm volatile("s_waitcnt vmcnt(6) lgkmcnt(0)" ::: "memory");
            __builtin_amdgcn_s_barrier();
            __builtin_amdgcn_sched_barrier(0);
            loadXA(kt + 2);
            stageB(bC, kt + 2);
            comp(bA);
            __builtin_amdgcn_sched_barrier(0);
            writeXB(bB);
            { int tmp = bA; bA = bB; bB = bC; bC = tmp; }
            // odd iter: load tile kt+3 -> B, write tile kt+2 from A
            asm volatile("s_waitcnt vmcnt(6) lgkmcnt(0)" ::: "memory");
            __builtin_amdgcn_s_barrier();
            __builtin_amdgcn_sched_barrier(0);
            loadXB(kt + 3);
            stageB(bC, kt + 3);
            comp(bA);
            __builtin_amdgcn_sched_barrier(0);
            writeXA(bB);
            { int tmp = bA; bA = bB; bB = bC; bC = tmp; }
        }
        // kt = 30: no more prefetch; tile 31 sits in regs B
        asm volatile("s_waitcnt vmcnt(6) lgkmcnt(0)" ::: "memory");
        __builtin_amdgcn_s_barrier();
        __builtin_amdgcn_sched_barrier(0);
        comp(bA);
        __builtin_amdgcn_sched_barrier(0);
        writeXB(bB);
        { int tmp = bA; bA = bB; bB = bC; bC = tmp; }
        // tile 31
        asm volatile("s_waitcnt vmcnt(0) lgkmcnt(0)" ::: "memory");
        __builtin_amdgcn_s_barrier();
        __builtin_amdgcn_sched_barrier(0);
        comp(bA);
    }
    __syncthreads();   // all reads done before Ct alias writes

    // f16 epilogue via LDS (scale folded for Q)
#pragma unroll
    for (int i = 0; i < 4; i++) {
        const int row = wm + i * 16 + quad * 4;
#pragma unroll
        for (int j = 0; j < 4; j++) {
            const int col = wn + j * 16 + l16;
            const float bv2 = bias[n0 + col];
#pragma unroll
            for (int r = 0; r < 2; r++) {
                union { h16x2 h; unsigned u; } P;
                P.h = __builtin_amdgcn_cvt_pkrtz((acc[i][j][2*r] + bv2) * scl,
                                                 (acc[i][j][2*r+1] + bv2) * scl);
                Ct[(row + 2*r)     * 136 + col] = (u16)(P.u & 0xFFFF);
                Ct[(row + 2*r + 1) * 136 + col] = (u16)(P.u >> 16);
            }
        }
    }
    __syncthreads();

    if (t < 2) {              // (B,H,S,Dk)
        const int row = tid >> 1, half = tid & 1;
        const int m = m0 + row, b = m >> 11, s = m & 2047;
        const int h = (n0 >> 6) + half;
        u16* o = dst + ((size_t)(b * 16 + h) * 2048 + s) * 64;
        const u16* src = Ct + row * 136 + half * 64;
#pragma unroll
        for (int j = 0; j < 64; j += 8) *(u16x8*)(o + j) = *(const u16x8*)(src + j);
    } else {                  // (B,H,Dk,S) transposed V
        const int col = tid >> 1, shalf = tid & 1;
        const int h = (n0 >> 6) + (col >> 6), d = col & 63;
        const int mb = m0 + shalf * 64, b = mb >> 11, sb = mb & 2047;
        u16* o = dst + (size_t)((b * 16 + h) * 64 + d) * 2048 + sb;
#pragma unroll
        for (int j0 = 0; j0 < 64; j0 += 8) {
            u16x8 tv;
#pragma unroll
            for (int j = 0; j < 8; j++) tv[j] = Ct[(shalf * 64 + j0 + j) * 136 + col];
            *(u16x8*)(o + j0) = tv;
        }
    }
}

// ---------------------------------------------------------------------------
// O-GEMM, BK=32, triple-buffered counted-vmcnt pipeline.
// MODE 2: X,W f16 GLDS.  MODE 1: X f16 GLDS + W fp32 reg-staged.
// ---------------------------------------------------------------------------
template<int MODE>
__global__ __launch_bounds__(256, 3) void gemm_o(
    const u16* __restrict__ Xb, const u16* __restrict__ wcO,
    const float* __restrict__ Wf, const float* __restrict__ bias,
    float* __restrict__ out)
{
    __shared__ __align__(16) u16 smem[24576];   // 3 x (As | Bs)

    const int tid  = threadIdx.x;
    const int wave = tid >> 6, lane = tid & 63;
    const int quad = lane >> 4, l16 = lane & 15;
    const int m0 = blockIdx.x * 128, n0 = blockIdx.y * 128;
    const int wm = (wave >> 1) * 64, wn = (wave & 1) * 64;

    const int srow = lane >> 2;
    const size_t scol = (size_t)(lane & 3) * 8;
    const int sr = tid >> 1, hh = tid & 1;

    f32x4 acc[4][4];
    for (int i = 0; i < 4; i++) for (int j = 0; j < 4; j++) acc[i][j] = f4zero();

    auto stageA = [&](int b, int kt) {
        GLDS(Xb + (size_t)(m0 + wave * 32 +      srow) * 1024 + kt * 32 + scol,
             smem + b * 8192 + wave * 1024);
        GLDS(Xb + (size_t)(m0 + wave * 32 + 16 + srow) * 1024 + kt * 32 + scol,
             smem + b * 8192 + wave * 1024 + 512);
    };
    auto stageB = [&](int b, int kt) {
        GLDS(wcO + (size_t)(n0 + wave * 32 +      srow) * 1024 + kt * 32 + scol,
             smem + b * 8192 + 4096 + wave * 1024);
        GLDS(wcO + (size_t)(n0 + wave * 32 + 16 + srow) * 1024 + kt * 32 + scol,
             smem + b * 8192 + 4096 + wave * 1024 + 512);
    };
    float4 wr_[4];
    auto loadW = [&](int kt) {
        const float* p = Wf + (size_t)(n0 + sr) * 1024 + kt * 32 + hh * 16;
        wr_[0] = *(const float4*)(p);     wr_[1] = *(const float4*)(p + 4);
        wr_[2] = *(const float4*)(p + 8); wr_[3] = *(const float4*)(p + 12);
    };
    auto writeW = [&](int b) {
        u16* d = smem + b * 8192 + 4096 + sr * 32 + hh * 16;
        *(u16x8*)d       = cvth8(wr_[0], wr_[1]);
        *(u16x8*)(d + 8) = cvth8(wr_[2], wr_[3]);
    };
    auto comp = [&](int b) {
        const u16* As = smem + b * 8192;
        const u16* Bs = As + 4096;
        f16x8 af[4], bfr[4];
#pragma unroll
        for (int i = 0; i < 4; i++) {
            af[i]  = *(const f16x8*)(As + (wm + i * 16 + l16) * 32 + quad * 8);
            bfr[i] = *(const f16x8*)(Bs + (wn + i * 16 + l16) * 32 + quad * 8);
        }
        __builtin_amdgcn_s_setprio(1);
#pragma unroll
        for (int i = 0; i < 4; i++)
#pragma unroll
            for (int j = 0; j < 4; j++)
                acc[i][j] = MFMA32F16(af[i], bfr[j], acc[i][j]);
        __builtin_amdgcn_s_setprio(0);
    };

    // prologue
    stageA(0, 0);
    if (MODE == 2) stageB(0, 0);
    stageA(1, 1);
    if (MODE == 2) stageB(1, 1);
    if (MODE == 1) { loadW(0); writeW(0); }
    int bA = 0, bB = 1, bC = 2;
    for (int kt = 0; kt < 31; ++kt) {
        if (MODE == 2) asm volatile("s_waitcnt vmcnt(4) lgkmcnt(0)" ::: "memory");
        else           asm volatile("s_waitcnt vmcnt(2) lgkmcnt(0)" ::: "memory");
        __builtin_amdgcn_s_barrier();
        __builtin_amdgcn_sched_barrier(0);
        if (MODE == 1) loadW(kt + 1);
        if (kt < 30) {
            stageA(bC, kt + 2);
            if (MODE == 2) stageB(bC, kt + 2);
        }
        comp(bA);
        if (MODE == 1) writeW(bB);
        int tmp = bA; bA = bB; bB = bC; bC = tmp;
    }
    asm volatile("s_waitcnt vmcnt(0) lgkmcnt(0)" ::: "memory");
    __builtin_amdgcn_s_barrier();
    __builtin_amdgcn_sched_barrier(0);
    comp(bA);

#pragma unroll
    for (int i = 0; i < 4; i++)
#pragma unroll
        for (int j = 0; j < 4; j++) {
            const int col = wn + j * 16 + l16;
            const float bv = bias[n0 + col];
#pragma unroll
            for (int r = 0; r < 4; r++)
                out[(size_t)(m0 + wm + i * 16 + quad * 4 + r) * 1024 + n0 + col] = acc[i][j][r] + bv;
        }
}

// ---------------------------------------------------------------------------
// Flash attention: fixed-shift softmax, l via ones-MFMA. (unchanged round-6)
// ---------------------------------------------------------------------------
__global__ __launch_bounds__(256, 4) void attn_fused(
    const u16* __restrict__ qh, const u16* __restrict__ kh,
    const u16* __restrict__ vth, const int* __restrict__ mask,
    u16* __restrict__ xout)
{
    __shared__ __align__(16) u16 Ksh[2][4096];    // [buf][row*64 + swz-chunk] linear
    __shared__ __align__(16) u16 Vsh[2][4352];    // [buf][d*68 + key] pad 68
    __shared__ float mshf[2][64];                 // per-key additive bias

    const int tid = threadIdx.x, wave = tid >> 6, lane = tid & 63;
    const int quad = lane >> 4, l16 = lane & 15;

    // XCD-aware remap: flat%8 == bh%8 for all 16 q-blocks of a given bh
    const int flat = blockIdx.x + (blockIdx.y << 4);   // gridDim.x == 16
    const int xr = flat & 7, xc_ = flat >> 3;
    const int qb = xc_ & 15, bh = xr + ((xc_ >> 4) << 3);
    const int b = bh >> 4, h = bh & 15;
    const int wq = qb * 128 + wave * 32;

    f16x8 qf[2][2];
#pragma unroll
    for (int qg = 0; qg < 2; qg++)
#pragma unroll
        for (int kc = 0; kc < 2; kc++)
            qf[qg][kc] = *(const f16x8*)(qh + ((size_t)bh * 2048 + wq + qg * 16 + l16) * 64
                                         + kc * 32 + quad * 8);

    f32x4 o[2][4];
#pragma unroll
    for (int qg = 0; qg < 2; qg++)
        for (int dt = 0; dt < 4; dt++) o[qg][dt] = f4zero();
    f32x4 lacc[2]; lacc[0] = f4zero(); lacc[1] = f4zero();
    f16x4 ones;
    ones[0] = (_Float16)1.f; ones[1] = (_Float16)1.f;
    ones[2] = (_Float16)1.f; ones[3] = (_Float16)1.f;

    const int klr = lane >> 3;                              // 0..7
    const size_t kgoff = (size_t)((lane & 7) ^ klr) << 3;   // elem offset in row
    const u16* kgb = kh + (size_t)bh * 2048 * 64;

    const int skey = tid >> 2, sc = (tid & 3) * 16;
    const u16* vg = vth + ((size_t)bh * 64 + skey) * 2048 + sc;
    const int mrow = b * 2048;

    {
        GLDS(kgb + (size_t)(wave * 16 + klr) * 64 + kgoff,     &Ksh[0][wave * 1024]);
        GLDS(kgb + (size_t)(wave * 16 + 8 + klr) * 64 + kgoff, &Ksh[0][wave * 1024 + 512]);
        const u16x8 v0 = *(const u16x8*)(vg);
        const u16x8 v1 = *(const u16x8*)(vg + 8);
        u16* vd = &Vsh[0][skey * 68 + sc];
        *(u16x4*)(vd)      = (u16x4){v0[0], v0[1], v0[2], v0[3]};
        *(u16x4*)(vd + 4)  = (u16x4){v0[4], v0[5], v0[6], v0[7]};
        *(u16x4*)(vd + 8)  = (u16x4){v1[0], v1[1], v1[2], v1[3]};
        *(u16x4*)(vd + 12) = (u16x4){v1[4], v1[5], v1[6], v1[7]};
        if (tid < 64) mshf[0][tid] = mask[mrow + tid] ? -10.0f : -1.0e30f;
    }
    __syncthreads();

    for (int t = 0; t < 32; ++t) {
        const int cur = t & 1;
        const u16* Kc = &Ksh[cur][0];
        const u16* Vc = &Vsh[cur][0];

        u16x8 v0, v1; int mreg = 1;
        const int kk2 = (t + 1) * 64;
        if (t < 31) {
            GLDS(kgb + (size_t)(kk2 + wave * 16 + klr) * 64 + kgoff,
                 &Ksh[cur ^ 1][wave * 1024]);
            GLDS(kgb + (size_t)(kk2 + wave * 16 + 8 + klr) * 64 + kgoff,
                 &Ksh[cur ^ 1][wave * 1024 + 512]);
            v0 = *(const u16x8*)(vg + kk2);
            v1 = *(const u16x8*)(vg + kk2 + 8);
            if (tid < 64) mreg = mask[mrow + kk2 + tid];
        }

        __builtin_amdgcn_s_setprio(1);
        // ---- phase 1: all QK^T + softmax -> pf[4][2] ----
        f16x4 pf[4][2];
#pragma unroll
        for (int nt = 0; nt < 4; nt++) {
            const int kro = (nt * 16 + l16) * 64;
            const f16x8 kf0 = *(const f16x8*)(Kc + kro + ((quad ^ (l16 & 7)) << 3));
            const f16x8 kf1 = *(const f16x8*)(Kc + kro + (((quad ^ 4) ^ (l16 & 7)) << 3));
            const float4 mb = *(const float4*)(&mshf[cur][nt * 16 + quad * 4]);
#pragma unroll
            for (int qg = 0; qg < 2; qg++) {
                f32x4 z;
                z[0] = mb.x; z[1] = mb.y; z[2] = mb.z; z[3] = mb.w;
                z = MFMA32F16(kf0, qf[qg][0], z);
                z = MFMA32F16(kf1, qf[qg][1], z);
                union { h16x2 h[2]; f16x4 v; } U;
                U.h[0] = __builtin_amdgcn_cvt_pkrtz(__builtin_amdgcn_exp2f(z[0]),
                                                    __builtin_amdgcn_exp2f(z[1]));
                U.h[1] = __builtin_amdgcn_cvt_pkrtz(__builtin_amdgcn_exp2f(z[2]),
                                                    __builtin_amdgcn_exp2f(z[3]));
                pf[nt][qg] = U.v;
            }
        }
        // ---- phase 2: dense PV + l MFMA cluster (register-only inputs) ----
#pragma unroll
        for (int nt = 0; nt < 4; nt++) {
            lacc[0] = MFMA16F16(ones, pf[nt][0], lacc[0]);
            lacc[1] = MFMA16F16(ones, pf[nt][1], lacc[1]);
        }
#pragma unroll
        for (int dt = 0; dt < 4; dt++) {
#pragma unroll
            for (int nt = 0; nt < 4; nt++) {
                const f16x4 vf = *(const f16x4*)(Vc + (dt * 16 + l16) * 68 + nt * 16 + quad * 4);
                o[0][dt] = MFMA16F16(vf, pf[nt][0], o[0][dt]);
                o[1][dt] = MFMA16F16(vf, pf[nt][1], o[1][dt]);
            }
        }
        __builtin_amdgcn_s_setprio(0);

        if (t < 31) {
            u16* vd = &Vsh[cur ^ 1][skey * 68 + sc];
            *(u16x4*)(vd)      = (u16x4){v0[0], v0[1], v0[2], v0[3]};
            *(u16x4*)(vd + 4)  = (u16x4){v0[4], v0[5], v0[6], v0[7]};
            *(u16x4*)(vd + 8)  = (u16x4){v1[0], v1[1], v1[2], v1[3]};
            *(u16x4*)(vd + 12) = (u16x4){v1[4], v1[5], v1[6], v1[7]};
            if (tid < 64) mshf[cur ^ 1][tid] = mreg ? -10.0f : -1.0e30f;
        }
        __syncthreads();
    }

#pragma unroll
    for (int qg = 0; qg < 2; qg++) {
        const float inv = 1.0f / lacc[qg][0];
        const int row = wq + qg * 16 + l16;
        u16* op = xout + ((size_t)b * 2048 + row) * 1024 + h * 64;
#pragma unroll
        for (int dt = 0; dt < 4; dt++) {
            union { h16x2 h[2]; u16x4 u; } U;
            U.h[0] = __builtin_amdgcn_cvt_pkrtz(o[qg][dt][0] * inv, o[qg][dt][1] * inv);
            U.h[1] = __builtin_amdgcn_cvt_pkrtz(o[qg][dt][2] * inv, o[qg][dt][3] * inv);
            *(u16x4*)(op + dt * 16 + quad * 4) = U.u;
        }
    }
}

extern "C" void kernel_launch(void* const* d_in, const int* in_sizes, int n_in,
                              void* d_out, int out_size, void* d_ws, size_t ws_size,
                              hipStream_t stream)
{
    const float* Q   = (const float*)d_in[0];
    const float* K   = (const float*)d_in[1];
    const float* V   = (const float*)d_in[2];
    const int*   msk = (const int*)d_in[3];
    const float* Wq  = (const float*)d_in[4];
    const float* bq  = (const float*)d_in[5];
    const float* Wk  = (const float*)d_in[6];
    const float* bk  = (const float*)d_in[7];
    const float* Wv  = (const float*)d_in[8];
    const float* bv  = (const float*)d_in[9];
    const float* Wo  = (const float*)d_in[10];
    const float* bo  = (const float*)d_in[11];

    u16* base = (u16*)d_ws;
    dim3 blk(256);
    dim3 gq(64, 24);         // fused QKV: 64 m-tiles x (3 tensors x 8 n-tiles)
    dim3 ga(16, 64);         // attn: 2048/128 q-blocks x BH
    dim3 go(64, 8);          // O-GEMM

    if (ws_size >= ((size_t)72 << 20)) {
        // wc(8M) + qkv(48M) + xs(16M) = 72 MiB
        u16* wc  = base;                                // 4x1M f16 weights
        u16* qhp = base + 4194304;                      // (B,H,S,64) f16
        u16* khp = qhp + 8388608;
        u16* vtp = khp + 8388608;                       // (B,H,64,S) f16
        u16* xs  = vtp + 8388608;                       // (B,S,1024) f16
        conv_w<<<1024, blk, 0, stream>>>(Wq, Wk, Wv, Wo, wc);
        gemm_qkv<1><<<gq, blk, 0, stream>>>(Q, K, V, wc,
            nullptr, nullptr, nullptr, bq, bk, bv, qhp, khp, vtp);
        attn_fused<<<ga, blk, 0, stream>>>(qhp, khp, vtp, msk, xs);
        gemm_o<2><<<go, blk, 0, stream>>>(xs, wc + 3 * 1048576, nullptr, bo, (float*)d_out);
    } else {
        u16* qhp = base;
        u16* khp = qhp + 8388608;
        u16* vtp = khp + 8388608;
        u16* xs  = vtp + 8388608;
        gemm_qkv<0><<<gq, blk, 0, stream>>>(Q, K, V, nullptr,
            Wq, Wk, Wv, bq, bk, bv, qhp, khp, vtp);
        attn_fused<<<ga, blk, 0, stream>>>(qhp, khp, vtp, msk, xs);
        gemm_o<1><<<go, blk, 0, stream>>>(xs, nullptr, Wo, bo, (float*)d_out);
    }
}